// Round 12
// baseline (242.200 us; speedup 1.0000x reference)
//
#include <hip/hip_runtime.h>
#include <hip/hip_bf16.h>
#include <cstdint>

#define B_ 8
#define N_ 512
#define D_ 256
#define E_ 16384
#define H_ 256

#define SA_STRIDE 56
#define SB_STRIDE 56
#define NSB 8      // scatter sub-blocks
#define SUBCAP 32  // per-(sub-block,src) capacity; Binom(2048,1/512)>=32 ~ 2e-17

using bf16x8 = __attribute__((ext_vector_type(8))) short;
using bf16x4 = __attribute__((ext_vector_type(4))) short;
using f32x4  = __attribute__((ext_vector_type(4))) float;

__device__ inline unsigned short f2bf(float f) {
    union { float f; unsigned u; } v; v.f = f;
    unsigned u = v.u;
    return (unsigned short)((u + 0x7fffu + ((u >> 16) & 1u)) >> 16);  // RNE
}

// init: blocks 0-31 transpose W1 halves -> W1T (512 n-rows x 256 k) bf16;
//       block 32 zeroes the grid-barrier words (1280 ints).
__global__ __launch_bounds__(256)
void init_k(const float* __restrict__ W1, unsigned short* __restrict__ W1T,
            int* __restrict__ bar) {
    const int tb = blockIdx.x, t = threadIdx.x;
    if (tb == 32) {
#pragma unroll
        for (int i = 0; i < 5; i++) bar[t + i * 256] = 0;
        return;
    }
    __shared__ float tile[64][65];
    const int h   = tb >> 4;
    const int rem = tb & 15;
    const int tk  = (rem >> 2) * 64;
    const int tn  = (rem & 3) * 64;
    const float* Wh = W1 + (size_t)h * 256 * 256;
    const int c = t & 63, r0 = t >> 6;
#pragma unroll
    for (int i = 0; i < 16; i++) {
        int r = r0 + i * 4;
        tile[r][c] = Wh[(size_t)(tk + r) * 256 + tn + c];
    }
    __syncthreads();
#pragma unroll
    for (int i = 0; i < 16; i++) {
        int rn = r0 + i * 4;
        W1T[(size_t)(h * 256 + tn + rn) * 256 + tk + c] = f2bf(tile[c][rn]);
    }
}

// tree grid barrier: 32 leaf counters (64B-spaced), root, 32 leaf-release flags.
// Requires all 1024 blocks co-resident (4/CU via launch_bounds + 32.3 KB LDS).
__device__ inline void grid_barrier(int* bar, int bid) {
    __syncthreads();
    __threadfence();                                   // release prior writes
    if (threadIdx.x == 0) {
        const int leaf = bid & 31;
        int prev = atomicAdd(&bar[leaf * 16], 1);
        if (prev == 31) {                              // last in leaf
            int r = atomicAdd(&bar[512], 1);
            if (r == 31) {                             // last leaf -> release
                __threadfence();
                for (int l = 0; l < 32; l++)
                    atomicExch(&bar[544 + l * 16], 1);
            }
        }
        while (atomicAdd(&bar[544 + leaf * 16], 0) == 0)
            __builtin_amdgcn_s_sleep(8);
    }
    __syncthreads();
    __threadfence();                                   // acquire
}

// 8 bf16 (u,v) pairs -> partial relu-dot (b1 already folded into u)
__device__ inline float dot8nb(uint4 qu, uint4 qv, const float* w2p) {
    unsigned us[4] = {qu.x, qu.y, qu.z, qu.w};
    unsigned vs[4] = {qv.x, qv.y, qv.z, qv.w};
    float p = 0.f;
#pragma unroll
    for (int j = 0; j < 4; j++) {
        float ulo = __uint_as_float(us[j] << 16);
        float uhi = __uint_as_float(us[j] & 0xffff0000u);
        float vlo = __uint_as_float(vs[j] << 16);
        float vhi = __uint_as_float(vs[j] & 0xffff0000u);
        float hlo = fmaxf(ulo + vlo, 0.f);
        float hhi = fmaxf(uhi + vhi, 0.f);
        p = fmaf(hlo, w2p[2 * j],     p);
        p = fmaf(hhi, w2p[2 * j + 1], p);
    }
    return p;
}

union SMem {
    struct {
        unsigned short sA[32 * SA_STRIDE];    // 3.6 KB
        unsigned short sB[256 * SB_STRIDE];   // 28.7 KB
    } g;
    int hist[512];
};

// Phase A: all blocks zero d_out slice; blocks 0-255 GEMM -> P bf16 (b1 folded
//   into U); blocks 256-263 sub-bucket edge scatter (plain stores, no init).
// Barrier. Phase B: all 1024 blocks bucketed edge scoring.
__global__ __launch_bounds__(256, 4)
void mega(const float* __restrict__ feat, const unsigned short* __restrict__ W1T,
          const float* __restrict__ b1, const float* __restrict__ W2,
          const float* __restrict__ b2, const int* __restrict__ eidx,
          float* __restrict__ out, unsigned short* __restrict__ P,
          int* __restrict__ gCnt8, int* __restrict__ gBucket,
          int* __restrict__ bar) {
    __shared__ SMem sm;
    const int bid = blockIdx.x;
    const int t   = threadIdx.x;

    // ---- phase A0: zero d_out (1024 blocks x 8 KB = 8 MB) ----
    {
        float4 z = make_float4(0.f, 0.f, 0.f, 0.f);
        float4* oz = (float4*)out + (size_t)bid * 512 + t;
        oz[0] = z; oz[256] = z;
    }

    if (bid >= 256 && bid < 264) {
        // ---- scatter: block owns 2048 edges, zero global atomics ----
        const int sb = bid - 256;
        for (int i = t; i < 512; i += 256) sm.hist[i] = 0;
        __syncthreads();
#pragma unroll
        for (int k = 0; k < 8; k++) {
            int e = sb * 2048 + k * 256 + t;
            int s = eidx[e];
            int d = eidx[E_ + e];
            int slot = atomicAdd(&sm.hist[s], 1);        // LDS atomic only
            gBucket[(s * NSB + sb) * SUBCAP + slot] = d;
        }
        __syncthreads();
        for (int s = t; s < 512; s += 256)
            gCnt8[s * NSB + sb] = sm.hist[s];            // plain store
    } else if (bid < 256) {
        // ---- GEMM: M-tile 32, P(4096,512) bf16 ----
        const int bm = bid >> 1;
        const int bn = bid & 1;
        const int m0 = bm * 32;

        const int arow = t >> 3;          // 32 rows, 8 threads/row
        const int akg  = (t & 7) * 4;     // 4 fp32 each
        const float* pA = feat + (size_t)(m0 + arow) * 256;
        const unsigned short* pB = W1T + (size_t)(bn * 256 + t) * 256;

        const int wave = t >> 6, lane = t & 63, l15 = lane & 15, quad = lane >> 4;

        f32x4 acc[2][4];
#pragma unroll
        for (int rm = 0; rm < 2; rm++)
#pragma unroll
            for (int cn = 0; cn < 4; cn++)
                acc[rm][cn] = (f32x4){0.f, 0.f, 0.f, 0.f};

        for (int k0 = 0; k0 < 256; k0 += 32) {
            __syncthreads();
            {
                float4 lo = *(const float4*)(pA + k0 + akg);
                union { bf16x4 v; unsigned short s[4]; } u;
                u.s[0] = f2bf(lo.x); u.s[1] = f2bf(lo.y);
                u.s[2] = f2bf(lo.z); u.s[3] = f2bf(lo.w);
                *(bf16x4*)(sm.g.sA + arow * SA_STRIDE + akg) = u.v;
            }
            {
                const unsigned short* p = pB + k0;
                uint4 q0 = *(const uint4*)(p);
                uint4 q1 = *(const uint4*)(p + 8);
                uint4 q2 = *(const uint4*)(p + 16);
                uint4 q3 = *(const uint4*)(p + 24);
                *(uint4*)(sm.g.sB + t * SB_STRIDE +  0) = q0;
                *(uint4*)(sm.g.sB + t * SB_STRIDE +  8) = q1;
                *(uint4*)(sm.g.sB + t * SB_STRIDE + 16) = q2;
                *(uint4*)(sm.g.sB + t * SB_STRIDE + 24) = q3;
            }
            __syncthreads();

            bf16x8 af[2], bfr[4];
#pragma unroll
            for (int rm = 0; rm < 2; rm++)
                af[rm] = *(const bf16x8*)(sm.g.sA + (rm * 16 + l15) * SA_STRIDE + quad * 8);
#pragma unroll
            for (int cn = 0; cn < 4; cn++)
                bfr[cn] = *(const bf16x8*)(sm.g.sB + (wave * 64 + cn * 16 + l15) * SB_STRIDE + quad * 8);
#pragma unroll
            for (int rm = 0; rm < 2; rm++)
#pragma unroll
                for (int cn = 0; cn < 4; cn++)
                    acc[rm][cn] = __builtin_amdgcn_mfma_f32_16x16x32_bf16(af[rm], bfr[cn], acc[rm][cn], 0, 0, 0);
        }

#pragma unroll
        for (int cn = 0; cn < 4; cn++) {
            int colh = wave * 64 + cn * 16 + l15;
            float bias = (bn == 0) ? b1[colh] : 0.f;
            int col = bn * 256 + colh;
#pragma unroll
            for (int rm = 0; rm < 2; rm++)
#pragma unroll
                for (int r = 0; r < 4; r++) {
                    int row = m0 + rm * 16 + quad * 4 + r;
                    P[(size_t)row * 512 + col] = f2bf(acc[rm][cn][r] + bias);
                }
        }
    }

    grid_barrier(bar, bid);

    // ---- phase B: edge scoring, 4 workers per (batch, src) bucket ----
    {
        const int b    = bid & 7;              // XCD-aligned batch
        const int q    = bid >> 3;             // 0..127
        const int lane = t & 63;
        const int wave = t >> 6;
        const int g    = lane >> 4;
        const int w    = lane & 15;
        const int wid  = wave * 4 + g;         // 0..15
        const int s    = q * 4 + (wid >> 2);   // src bucket
        const int o    = wid & 3;              // 4 workers per bucket

        const int* cp = gCnt8 + s * NSB;
        int4 c0 = *(const int4*)cp;
        int4 c1 = *(const int4*)(cp + 4);
        int pre[9];
        pre[0] = 0;
        pre[1] = pre[0] + c0.x; pre[2] = pre[1] + c0.y;
        pre[3] = pre[2] + c0.z; pre[4] = pre[3] + c0.w;
        pre[5] = pre[4] + c1.x; pre[6] = pre[5] + c1.y;
        pre[7] = pre[6] + c1.z; pre[8] = pre[7] + c1.w;
        const int en = pre[8];
        const int* bucket = gBucket + s * (NSB * SUBCAP);

        float w2r[16];
#pragma unroll
        for (int j = 0; j < 4; j++)
            *(float4*)(w2r + 4 * j) = *(const float4*)(W2 + w * 16 + 4 * j);
        const float b2v = b2[0];

        const unsigned short* Pu = P + ((size_t)b * 512 + s) * 512 + w * 16;
        uint4 u0 = *(const uint4*)(Pu);
        uint4 u1 = *(const uint4*)(Pu + 8);
        const unsigned short* Pv = P + (size_t)b * 512 * 512 + 256 + w * 16;
        float* outb = out + ((size_t)b * 512 + s) * 512;

        auto fetch = [&](int j) -> int {
            int i = 0;
#pragma unroll
            for (int qq = 1; qq < 8; qq++) i += (j >= pre[qq]);
            return bucket[i * SUBCAP + (j - pre[i])];
        };

        int j = o;
        int dst0 = 0; uint4 v00 = {}, v01 = {};
        if (j < en) {
            dst0 = fetch(j);
            const unsigned short* pv = Pv + (size_t)dst0 * 512;
            v00 = *(const uint4*)pv; v01 = *(const uint4*)(pv + 8);
        }
        while (j < en) {
            int jn = j + 4;
            int dst1 = 0; uint4 v10 = {}, v11 = {};
            if (jn < en) {
                dst1 = fetch(jn);
                const unsigned short* pv = Pv + (size_t)dst1 * 512;
                v10 = *(const uint4*)pv; v11 = *(const uint4*)(pv + 8);
            }
            float p = dot8nb(u0, v00, w2r) + dot8nb(u1, v01, w2r + 8);
            p += __shfl_xor(p, 1);
            p += __shfl_xor(p, 2);
            p += __shfl_xor(p, 4);
            p += __shfl_xor(p, 8);
            if (w == 0) {
                float sv = 1.0f / (1.0f + __expf(-(p + b2v)));
                outb[dst0] = sv;
            }
            dst0 = dst1; v00 = v10; v01 = v11; j = jn;
        }
    }
}

extern "C" void kernel_launch(void* const* d_in, const int* in_sizes, int n_in,
                              void* d_out, int out_size, void* d_ws, size_t ws_size,
                              hipStream_t stream) {
    const float* feat = (const float*)d_in[0];
    const float* W1   = (const float*)d_in[1];
    const float* b1   = (const float*)d_in[2];
    const float* W2   = (const float*)d_in[3];
    const float* b2   = (const float*)d_in[4];
    const int*   eidx = (const int*)d_in[5];
    float* out = (float*)d_out;

    unsigned short* W1T = (unsigned short*)d_ws;                        // 256 KB
    unsigned short* P   = (unsigned short*)((char*)d_ws + (1 << 20));   // 4 MB
    int* gCnt8   = (int*)((char*)d_ws + (6 << 20));                     // 16 KB
    int* gBucket = (int*)((char*)d_ws + (6 << 20) + (1 << 16));         // 512 KB
    int* bar     = (int*)((char*)d_ws + (7 << 20));                     // 8 KB

    init_k<<<33, 256, 0, stream>>>(W1, W1T, bar);
    mega<<<1024, 256, 0, stream>>>(feat, W1T, b1, W2, b2, eidx,
                                   out, P, gCnt8, gBucket, bar);
}